// Round 10
// baseline (13136.269 us; speedup 1.0000x reference)
//
#include <hip/hip_runtime.h>

typedef _Float16 half8   __attribute__((ext_vector_type(8)));
typedef _Float16 half2_t __attribute__((ext_vector_type(2)));
typedef float    floatx4 __attribute__((ext_vector_type(4)));
typedef unsigned int uintx4 __attribute__((ext_vector_type(4)));
typedef unsigned int uint32;

__device__ __forceinline__ float sigm(float v) { return 1.0f / (1.0f + __expf(-v)); }

__device__ __forceinline__ float fdot2h(uint32 w, uint32 h, float c) {
#if __has_builtin(__builtin_amdgcn_fdot2)
  return __builtin_amdgcn_fdot2(__builtin_bit_cast(half2_t, w), __builtin_bit_cast(half2_t, h), c, false);
#else
  half2_t a = __builtin_bit_cast(half2_t, w), b = __builtin_bit_cast(half2_t, h);
  return c + (float)a[0] * (float)b[0] + (float)a[1] * (float)b[1];
#endif
}

__device__ __forceinline__ uint32 pack_rte(float a, float b) {
  half2_t h; h[0] = (_Float16)a; h[1] = (_Float16)b;
  return __builtin_bit_cast(uint32, h);
}

// ---------------- pack W_ih + W_hh: f32 -> f16 pairs (RTE), flat ----------------
__global__ __launch_bounds__(256) void pack_w(const float* __restrict__ wih, const float* __restrict__ whh,
                                              uint32* __restrict__ wihd, uint32* __restrict__ whhd) {
  for (int p = blockIdx.x * 256 + threadIdx.x; p < 1572864; p += 262144) {
    if (p < 1048576) {
      wihd[p] = pack_rte(wih[2 * p], wih[2 * p + 1]);
    } else {
      int q = p - 1048576;
      whhd[q] = pack_rte(whh[2 * q], whh[2 * q + 1]);
    }
  }
}

// ---------------- pack one CT=32 chunk of x slices: xs[k][R=b*32+ct][512] f16 ----------------
__global__ __launch_bounds__(256) void pack_xc(const float* __restrict__ x, uint32* __restrict__ xsd, int t0) {
  for (int p = blockIdx.x * 256 + threadIdx.x; p < 2097152; p += 524288) {
    int k   = p >> 19;
    int R   = (p >> 8) & 2047;   // R = b*32 + ct
    int pc  = p & 255;
    int b = R >> 5, ct = R & 31;
    int sk = (k * 1024) / 6;     // 0,170,341,512
    const float* src = x + ((size_t)(t0 + ct) * 64 + b) * 1024 + sk + pc * 2;
    xsd[p] = pack_rte(src[0], src[1]);
  }
}

// ---------------- phase 1: xg16 = xs @ Wih^T + bias via f16 MFMA (unchanged, verified) ----------------
__global__ __launch_bounds__(256) void gemm16(const _Float16* __restrict__ xs,
                                              const _Float16* __restrict__ wih16,
                                              const float* __restrict__ bih,
                                              const float* __restrict__ bhh,
                                              _Float16* __restrict__ xg) {
  __shared__ _Float16 SL[18432];
  const int tid = threadIdx.x;
  const int bid = blockIdx.x;
  const int nt = bid & 7, mt = (bid >> 3) & 15, kb = bid >> 7;
  const int l = tid & 63;
  const int wid = tid >> 6;
  const int wm = wid >> 1, wn = wid & 1;
  const int lr = l & 15, lk = l >> 4;

  floatx4 acc[4][4] = {};
  const _Float16* xsk = xs + ((size_t)kb << 20);
  const _Float16* wk  = wih16 + ((size_t)kb << 19);

  for (int kt = 0; kt < 8; ++kt) {
    const int K0 = kt * 64;
    half8 av[4], bv[4];
#pragma unroll
    for (int q = 0; q < 4; ++q) {
      int s = q * 256 + tid;
      int row = s >> 3, c8 = s & 7;
      av[q] = *(const half8*)(xsk + (size_t)(mt * 128 + row) * 512 + K0 + c8 * 8);
      bv[q] = *(const half8*)(wk  + (size_t)(nt * 128 + row) * 512 + K0 + c8 * 8);
    }
#pragma unroll
    for (int q = 0; q < 4; ++q) {
      int s = q * 256 + tid;
      int row = s >> 3, c8 = s & 7;
      *(half8*)&SL[row * 72 + c8 * 8]        = av[q];
      *(half8*)&SL[9216 + row * 72 + c8 * 8] = bv[q];
    }
    __syncthreads();
#pragma unroll
    for (int ks = 0; ks < 2; ++ks) {
      half8 af[4], bf[4];
#pragma unroll
      for (int fm = 0; fm < 4; ++fm)
        af[fm] = *(const half8*)&SL[(wm * 64 + fm * 16 + lr) * 72 + (ks * 4 + lk) * 8];
#pragma unroll
      for (int fn = 0; fn < 4; ++fn)
        bf[fn] = *(const half8*)&SL[9216 + (wn * 64 + fn * 16 + lr) * 72 + (ks * 4 + lk) * 8];
#pragma unroll
      for (int fm = 0; fm < 4; ++fm)
#pragma unroll
        for (int fn = 0; fn < 4; ++fn)
          acc[fm][fn] = __builtin_amdgcn_mfma_f32_16x16x32_f16(af[fm], bf[fn], acc[fm][fn], 0, 0, 0);
    }
    __syncthreads();
  }
  float bias[4];
#pragma unroll
  for (int fn = 0; fn < 4; ++fn) {
    int g = nt * 128 + wn * 64 + fn * 16 + lr;
    bias[fn] = bih[kb * 1024 + g] + bhh[kb * 1024 + g];
  }
#pragma unroll
  for (int fm = 0; fm < 4; ++fm)
#pragma unroll
    for (int fn = 0; fn < 4; ++fn) {
      int colb = wn * 64 + fn * 16 + lr;
#pragma unroll
      for (int r = 0; r < 4; ++r) {
        int rowb = wm * 64 + fm * 16 + lk * 4 + r;
        SL[rowb * 128 + colb] = (_Float16)(acc[fm][fn][r] + bias[fn]);
      }
    }
  __syncthreads();
#pragma unroll
  for (int q = 0; q < 8; ++q) {
    int s = q * 256 + tid;
    int row = s >> 4, c16 = s & 15;
    int R = mt * 128 + row;
    size_t off = ((size_t)(kb * 64 + (R >> 5)) * 32 + (R & 31)) * 1024 + nt * 128 + c16 * 8;
    *(uintx4*)(xg + off) = *(const uintx4*)&SL[row * 128 + c16 * 8];
  }
}

// ---------------- phase 2: 256 chains, 1 block/(k,b), 256 threads, CT=32 steps ----------------
// Thread j owns ALL FOUR gate rows of hidden j: (j, 256+j, 512+j, 768+j) -> no gate exchange.
// Weights per thread = 128 quads: 44 named VGPR quads + 64 AGPR quads (inline-asm accvgpr
// pin; per-wave budget at 1 wave/SIMD = 512 regs) + 20 quads in LDS. Zero per-step L2 traffic.
// LDS dw: [0,256) hl[2][256 f16] | [256,4352) slab 8x1024 f16 | [4352,8448) hist 32x256 f16
//         | [8448,28928) wl 20*256 quads.  Total 115,712 B -> 1 block/CU, 1 wave/SIMD.
__global__ __attribute__((amdgpu_flat_work_group_size(256, 256), amdgpu_waves_per_eu(1, 1)))
void lstm32(const _Float16* __restrict__ xg,
            const uint32* __restrict__ whh16,
            const float* __restrict__ h0,
            const float* __restrict__ c0,
            float* __restrict__ out,
            float* __restrict__ state, int t0, int last) {
  extern __shared__ uint32 lds[];
  const uintx4*  hl4  = (const uintx4*)lds;            // 2 x 32 quads
  _Float16*      hl16 = (_Float16*)lds;
  const _Float16* xsl = (const _Float16*)(lds + 256);  // slab: 8 steps x 1024 gates
  _Float16*      hist = (_Float16*)(lds + 4352);       // 32 x 256 f16
  uintx4*        wl4  = (uintx4*)(lds + 8448);         // 20*256 quads
  const int tid = threadIdx.x;                          // = hidden index j
  const int k = blockIdx.x >> 6, b = blockIdx.x & 63;

  // row bases: gate g row = g*256 + j ; each row = 32 quads
  const uintx4* wr0 = (const uintx4*)(whh16 + ((size_t)(k * 1024 + tid) << 7));
  const uintx4* wr1 = wr0 + 8192;    // +256 rows * 32 quads
  const uintx4* wr2 = wr0 + 16384;
  const uintx4* wr3 = wr0 + 24576;

  // ---- 44 VGPR-resident quads (11 per gate row) ----
#define DECL_VQ(g,i) uintx4 V##g##_##i = wr##g[i];
#define FOR_I11(X,g) X(g,0) X(g,1) X(g,2) X(g,3) X(g,4) X(g,5) X(g,6) X(g,7) X(g,8) X(g,9) X(g,10)
  FOR_I11(DECL_VQ,0) FOR_I11(DECL_VQ,1) FOR_I11(DECL_VQ,2) FOR_I11(DECL_VQ,3)

  // ---- 64 AGPR-resident quads (16 per gate row), pinned via accvgpr asm ----
#define DECL_AQ(g,i) uint32 A##g##_##i##_0, A##g##_##i##_1, A##g##_##i##_2, A##g##_##i##_3;
#define FOR_I16(X,g) X(g,0) X(g,1) X(g,2) X(g,3) X(g,4) X(g,5) X(g,6) X(g,7) X(g,8) X(g,9) X(g,10) X(g,11) X(g,12) X(g,13) X(g,14) X(g,15)
  FOR_I16(DECL_AQ,0) FOR_I16(DECL_AQ,1) FOR_I16(DECL_AQ,2) FOR_I16(DECL_AQ,3)
#define LOAD_AQ(g,i) { uintx4 s_ = wr##g[11 + i]; \
  asm("v_accvgpr_write_b32 %0, %4\n\tv_accvgpr_write_b32 %1, %5\n\tv_accvgpr_write_b32 %2, %6\n\tv_accvgpr_write_b32 %3, %7" \
      : "=a"(A##g##_##i##_0), "=a"(A##g##_##i##_1), "=a"(A##g##_##i##_2), "=a"(A##g##_##i##_3) \
      : "v"(s_[0]), "v"(s_[1]), "v"(s_[2]), "v"(s_[3])); }
  FOR_I16(LOAD_AQ,0) FOR_I16(LOAD_AQ,1) FOR_I16(LOAD_AQ,2) FOR_I16(LOAD_AQ,3)
#define AR(g,i) ({ uint32 t0_, t1_, t2_, t3_; \
  asm("v_accvgpr_read_b32 %0, %4\n\tv_accvgpr_read_b32 %1, %5\n\tv_accvgpr_read_b32 %2, %6\n\tv_accvgpr_read_b32 %3, %7" \
      : "=v"(t0_), "=v"(t1_), "=v"(t2_), "=v"(t3_) \
      : "a"(A##g##_##i##_0), "a"(A##g##_##i##_1), "a"(A##g##_##i##_2), "a"(A##g##_##i##_3)); \
  (uintx4){t0_, t1_, t2_, t3_}; })

  // ---- 20 LDS-resident quads (5 per gate row), lane-consecutive 16B ----
#pragma unroll
  for (int l = 0; l < 5; ++l) {
    wl4[(0 * 5 + l) * 256 + tid] = wr0[27 + l];
    wl4[(1 * 5 + l) * 256 + tid] = wr1[27 + l];
    wl4[(2 * 5 + l) * 256 + tid] = wr2[27 + l];
    wl4[(3 * 5 + l) * 256 + tid] = wr3[27 + l];
  }

  const _Float16* xgp = xg + (size_t)(k * 64 + b) * 32768;  // 32 steps * 1024 gates
  // slab window 0 (steps 0-7)
#pragma unroll
  for (int q = 0; q < 4; ++q)
    __builtin_amdgcn_global_load_lds((const __attribute__((address_space(1))) void*)(xgp + q * 2048 + tid * 8),
                                     (__attribute__((address_space(3))) void*)(lds + 256 + q * 1024 + tid * 4),
                                     16, 0, 0);

  float cst, hlast;
  {
    int gi = b * 1024 + k * 256 + tid;
    int si = (k * 64 + b) * 256 + tid;
    float hv, cv;
    if (t0 == 0) { hv = h0[gi]; cv = c0[gi]; }
    else         { hv = state[si]; cv = state[65536 + si]; }
    cst = cv; hlast = hv;
    hl16[tid] = (_Float16)hv;    // init hl buffer 0
  }
  asm volatile("s_waitcnt vmcnt(0)" ::: "memory");
  __builtin_amdgcn_sched_barrier(0);
  __syncthreads();

#define FD2(W, sa, sb) sa = fdot2h(W[0], hq[0], sa); sb = fdot2h(W[1], hq[1], sb); \
                       sa = fdot2h(W[2], hq[2], sa); sb = fdot2h(W[3], hq[3], sb);
#define QV(q) { uintx4 hq = hl4[hb + q]; FD2(V0_##q, s0a, s0b) FD2(V1_##q, s1a, s1b) FD2(V2_##q, s2a, s2b) FD2(V3_##q, s3a, s3b) }
#define QA(q, i) { uintx4 hq = hl4[hb + q]; \
  { uintx4 w_ = AR(0, i); FD2(w_, s0a, s0b) } { uintx4 w_ = AR(1, i); FD2(w_, s1a, s1b) } \
  { uintx4 w_ = AR(2, i); FD2(w_, s2a, s2b) } { uintx4 w_ = AR(3, i); FD2(w_, s3a, s3b) } }
#define QL(q, l) { uintx4 hq = hl4[hb + q]; \
  { uintx4 w_ = wl4[(0 * 5 + l) * 256 + tid]; FD2(w_, s0a, s0b) } \
  { uintx4 w_ = wl4[(1 * 5 + l) * 256 + tid]; FD2(w_, s1a, s1b) } \
  { uintx4 w_ = wl4[(2 * 5 + l) * 256 + tid]; FD2(w_, s2a, s2b) } \
  { uintx4 w_ = wl4[(3 * 5 + l) * 256 + tid]; FD2(w_, s3a, s3b) } }

#pragma unroll 1
  for (int ct = 0; ct < 32; ++ct) {
    if (ct && !(ct & 7)) {   // refresh slab window ct/8 (steps ct..ct+7)
      const int w = ct >> 3;
#pragma unroll
      for (int q = 0; q < 4; ++q)
        __builtin_amdgcn_global_load_lds((const __attribute__((address_space(1))) void*)(xgp + w * 8192 + q * 2048 + tid * 8),
                                         (__attribute__((address_space(3))) void*)(lds + 256 + q * 1024 + tid * 4),
                                         16, 0, 0);
      asm volatile("s_waitcnt vmcnt(0)" ::: "memory");
      __builtin_amdgcn_sched_barrier(0);
      __syncthreads();
    }
    const int hb = (ct & 1) * 32;     // hl read buffer (quads)
    float xgi = (float)xsl[(ct & 7) * 1024 + tid];
    float xgf = (float)xsl[(ct & 7) * 1024 + 256 + tid];
    float xgg = (float)xsl[(ct & 7) * 1024 + 512 + tid];
    float xgo = (float)xsl[(ct & 7) * 1024 + 768 + tid];

    float s0a = 0.f, s0b = 0.f, s1a = 0.f, s1b = 0.f;
    float s2a = 0.f, s2b = 0.f, s3a = 0.f, s3b = 0.f;
    QV(0) QV(1) QV(2) QV(3) QV(4) QV(5) QV(6) QV(7) QV(8) QV(9) QV(10)
    QA(11,0) QA(12,1) QA(13,2) QA(14,3) QA(15,4) QA(16,5) QA(17,6) QA(18,7)
    QA(19,8) QA(20,9) QA(21,10) QA(22,11) QA(23,12) QA(24,13) QA(25,14) QA(26,15)
    QL(27,0) QL(28,1) QL(29,2) QL(30,3) QL(31,4)

    float iv = xgi + (s0a + s0b);
    float fv = xgf + (s1a + s1b);
    float gv = xgg + (s2a + s2b);
    float ov = xgo + (s3a + s3b);
    float cn = sigm(fv) * cst + sigm(iv) * tanhf(gv);
    float hn = sigm(ov) * tanhf(cn);
    cst = cn; hlast = hn;
    hist[ct * 256 + tid] = (_Float16)hn;
    hl16[(((ct & 1) ^ 1) << 8) + tid] = (_Float16)hn;   // next step's h buffer
    __syncthreads();
  }
#undef FD2
#undef QV
#undef QA
#undef QL

  // dump h history -> out (coalesced f32)
#pragma unroll 1
  for (int q = 0; q < 32; ++q)
    out[((size_t)(t0 + q) * 64 + b) * 1024 + k * 256 + tid] = (float)hist[q * 256 + tid];
  {
    int si = (k * 64 + b) * 256 + tid;
    state[si] = hlast;
    state[65536 + si] = cst;
    if (last) {
      int gi = b * 1024 + k * 256 + tid;
      out[33554432 + gi] = hlast;            // new_h
      out[33554432 + 65536 + gi] = cst;      // new_c
    }
  }
}

extern "C" void kernel_launch(void* const* d_in, const int* in_sizes, int n_in,
                              void* d_out, int out_size, void* d_ws, size_t ws_size,
                              hipStream_t stream) {
  const float* x   = (const float*)d_in[0];
  const float* h0  = (const float*)d_in[1];
  const float* c0  = (const float*)d_in[2];
  const float* Wih = (const float*)d_in[3];
  const float* Whh = (const float*)d_in[4];
  const float* bih = (const float*)d_in[5];
  const float* bhh = (const float*)d_in[6];
  float* out = (float*)d_out;
  char* ws = (char*)d_ws;

  // total ws usage: 31,981,568 B (under the known-good 36.2 MB)
  _Float16* xg16  = (_Float16*)ws;                  // 16,777,216 B
  _Float16* xs    = (_Float16*)(ws + 16777216L);    //  8,388,608 B
  _Float16* wih16 = (_Float16*)(ws + 25165824L);    //  4,194,304 B
  uint32*   whh16 = (uint32*)(ws + 29360128L);      //  2,097,152 B (f16 pairs)
  float*    state = (float*)(ws + 31457280L);       //    524,288 B

  hipFuncSetAttribute((const void*)lstm32, hipFuncAttributeMaxDynamicSharedMemorySize, 115712);

  pack_w<<<1024, 256, 0, stream>>>(Wih, Whh, (uint32*)wih16, whh16);
  for (int c = 0; c < 16; ++c) {
    int t0 = c * 32;
    pack_xc<<<2048, 256, 0, stream>>>(x, (uint32*)xs, t0);
    gemm16<<<512, 256, 0, stream>>>(xs, wih16, bih, bhh, xg16);
    lstm32<<<256, 256, 115712, stream>>>(xg16, whh16, h0, c0, out, state, t0, (c == 15) ? 1 : 0);
  }
}

// Round 11
// 1603.908 us; speedup vs baseline: 8.1902x; 8.1902x over previous
//
#include <hip/hip_runtime.h>

typedef _Float16 half8   __attribute__((ext_vector_type(8)));
typedef _Float16 half2_t __attribute__((ext_vector_type(2)));
typedef float    floatx4 __attribute__((ext_vector_type(4)));
typedef unsigned int uintx4 __attribute__((ext_vector_type(4)));
typedef unsigned int uint32;

__device__ __forceinline__ float sigm(float v) { return 1.0f / (1.0f + __expf(-v)); }

__device__ __forceinline__ float fdot2h(uint32 w, uint32 h, float c) {
#if __has_builtin(__builtin_amdgcn_fdot2)
  return __builtin_amdgcn_fdot2(__builtin_bit_cast(half2_t, w), __builtin_bit_cast(half2_t, h), c, false);
#else
  half2_t a = __builtin_bit_cast(half2_t, w), b = __builtin_bit_cast(half2_t, h);
  return c + (float)a[0] * (float)b[0] + (float)a[1] * (float)b[1];
#endif
}

__device__ __forceinline__ uint32 pack_rte(float a, float b) {
  half2_t h; h[0] = (_Float16)a; h[1] = (_Float16)b;
  return __builtin_bit_cast(uint32, h);
}

// ---------------- pack W_ih + W_hh: f32 -> f16 pairs (RTE), flat ----------------
__global__ __launch_bounds__(256) void pack_w(const float* __restrict__ wih, const float* __restrict__ whh,
                                              uint32* __restrict__ wihd, uint32* __restrict__ whhd) {
  for (int p = blockIdx.x * 256 + threadIdx.x; p < 1572864; p += 262144) {
    if (p < 1048576) {
      wihd[p] = pack_rte(wih[2 * p], wih[2 * p + 1]);
    } else {
      int q = p - 1048576;
      whhd[q] = pack_rte(whh[2 * q], whh[2 * q + 1]);
    }
  }
}

// ---------------- pack one CT=32 chunk of x slices: xs[k][R=b*32+ct][512] f16 ----------------
__global__ __launch_bounds__(256) void pack_xc(const float* __restrict__ x, uint32* __restrict__ xsd, int t0) {
  for (int p = blockIdx.x * 256 + threadIdx.x; p < 2097152; p += 524288) {
    int k   = p >> 19;
    int R   = (p >> 8) & 2047;   // R = b*32 + ct
    int pc  = p & 255;
    int b = R >> 5, ct = R & 31;
    int sk = (k * 1024) / 6;     // 0,170,341,512
    const float* src = x + ((size_t)(t0 + ct) * 64 + b) * 1024 + sk + pc * 2;
    xsd[p] = pack_rte(src[0], src[1]);
  }
}

// ---------------- phase 1: xg16 = xs @ Wih^T + bias via f16 MFMA (unchanged, verified) ----------------
__global__ __launch_bounds__(256) void gemm16(const _Float16* __restrict__ xs,
                                              const _Float16* __restrict__ wih16,
                                              const float* __restrict__ bih,
                                              const float* __restrict__ bhh,
                                              _Float16* __restrict__ xg) {
  __shared__ _Float16 SL[18432];
  const int tid = threadIdx.x;
  const int bid = blockIdx.x;
  const int nt = bid & 7, mt = (bid >> 3) & 15, kb = bid >> 7;
  const int l = tid & 63;
  const int wid = tid >> 6;
  const int wm = wid >> 1, wn = wid & 1;
  const int lr = l & 15, lk = l >> 4;

  floatx4 acc[4][4] = {};
  const _Float16* xsk = xs + ((size_t)kb << 20);
  const _Float16* wk  = wih16 + ((size_t)kb << 19);

  for (int kt = 0; kt < 8; ++kt) {
    const int K0 = kt * 64;
    half8 av[4], bv[4];
#pragma unroll
    for (int q = 0; q < 4; ++q) {
      int s = q * 256 + tid;
      int row = s >> 3, c8 = s & 7;
      av[q] = *(const half8*)(xsk + (size_t)(mt * 128 + row) * 512 + K0 + c8 * 8);
      bv[q] = *(const half8*)(wk  + (size_t)(nt * 128 + row) * 512 + K0 + c8 * 8);
    }
#pragma unroll
    for (int q = 0; q < 4; ++q) {
      int s = q * 256 + tid;
      int row = s >> 3, c8 = s & 7;
      *(half8*)&SL[row * 72 + c8 * 8]        = av[q];
      *(half8*)&SL[9216 + row * 72 + c8 * 8] = bv[q];
    }
    __syncthreads();
#pragma unroll
    for (int ks = 0; ks < 2; ++ks) {
      half8 af[4], bf[4];
#pragma unroll
      for (int fm = 0; fm < 4; ++fm)
        af[fm] = *(const half8*)&SL[(wm * 64 + fm * 16 + lr) * 72 + (ks * 4 + lk) * 8];
#pragma unroll
      for (int fn = 0; fn < 4; ++fn)
        bf[fn] = *(const half8*)&SL[9216 + (wn * 64 + fn * 16 + lr) * 72 + (ks * 4 + lk) * 8];
#pragma unroll
      for (int fm = 0; fm < 4; ++fm)
#pragma unroll
        for (int fn = 0; fn < 4; ++fn)
          acc[fm][fn] = __builtin_amdgcn_mfma_f32_16x16x32_f16(af[fm], bf[fn], acc[fm][fn], 0, 0, 0);
    }
    __syncthreads();
  }
  float bias[4];
#pragma unroll
  for (int fn = 0; fn < 4; ++fn) {
    int g = nt * 128 + wn * 64 + fn * 16 + lr;
    bias[fn] = bih[kb * 1024 + g] + bhh[kb * 1024 + g];
  }
#pragma unroll
  for (int fm = 0; fm < 4; ++fm)
#pragma unroll
    for (int fn = 0; fn < 4; ++fn) {
      int colb = wn * 64 + fn * 16 + lr;
#pragma unroll
      for (int r = 0; r < 4; ++r) {
        int rowb = wm * 64 + fm * 16 + lk * 4 + r;
        SL[rowb * 128 + colb] = (_Float16)(acc[fm][fn][r] + bias[fn]);
      }
    }
  __syncthreads();
#pragma unroll
  for (int q = 0; q < 8; ++q) {
    int s = q * 256 + tid;
    int row = s >> 4, c16 = s & 15;
    int R = mt * 128 + row;
    size_t off = ((size_t)(kb * 64 + (R >> 5)) * 32 + (R & 31)) * 1024 + nt * 128 + c16 * 8;
    *(uintx4*)(xg + off) = *(const uintx4*)&SL[row * 128 + c16 * 8];
  }
}

// ---------------- phase 2: 256 chains, 1 block/(k,b), 512 threads, CT=32 steps ----------------
// Pair-lane layout (r8-verified): thread 2j owns rows (j, 256+j) = (i,f); thread 2j+1 owns
// (512+j, 768+j) = (g,o); gates exchanged via shfl_xor(1). Weights per thread = 64 quads:
// 46 named VGPR quads with asm keep-alives (blocks rematerialization -> truly register-resident;
// budget 256 at 2 waves/SIMD, need ~230) + 18 quads in LDS (147 KB). Per-step weight L2 traffic
// -> zero (was 37 TB/s = the r7-r9 binding constraint). One barrier/step; h via LDS dbuf;
// out-store of h(ct-1) issued at top of step ct so its ack drains free at the end barrier.
__global__ __launch_bounds__(512, 2)
void lstm32(const _Float16* __restrict__ xg,
            const uint32* __restrict__ whh16,
            const float* __restrict__ h0,
            const float* __restrict__ c0,
            float* __restrict__ out,
            float* __restrict__ state, int t0, int last) {
  extern __shared__ uint32 lds[];
  const uintx4* hl4  = (const uintx4*)lds;       // hl[2][32 quads] = 2 x 256 f16
  _Float16*     hl16 = (_Float16*)lds;
  uintx4*       wl4  = (uintx4*)(lds + 256);     // 18*512 quads = 147456 B
  const int tid = threadIdx.x;
  const int k = blockIdx.x >> 6, b = blockIdx.x & 63;
  const int j = tid >> 1;        // hidden index of this lane pair
  const int half = tid & 1;      // 0 -> rows (j, 256+j); 1 -> (512+j, 768+j)
  const int r0 = j + half * 512;
  const int r1 = r0 + 256;

  const uintx4* w0q = (const uintx4*)(whh16 + ((size_t)(k * 1024 + r0) << 7));
  const uintx4* w1q = (const uintx4*)(whh16 + ((size_t)(k * 1024 + r1) << 7));
  // 46 VGPR-resident quads (23 per row)
  uintx4 A0  = w0q[0],  A1  = w0q[1],  A2  = w0q[2],  A3  = w0q[3],  A4  = w0q[4];
  uintx4 A5  = w0q[5],  A6  = w0q[6],  A7  = w0q[7],  A8  = w0q[8],  A9  = w0q[9];
  uintx4 A10 = w0q[10], A11 = w0q[11], A12 = w0q[12], A13 = w0q[13], A14 = w0q[14];
  uintx4 A15 = w0q[15], A16 = w0q[16], A17 = w0q[17], A18 = w0q[18], A19 = w0q[19];
  uintx4 A20 = w0q[20], A21 = w0q[21], A22 = w0q[22];
  uintx4 B0  = w1q[0],  B1  = w1q[1],  B2  = w1q[2],  B3  = w1q[3],  B4  = w1q[4];
  uintx4 B5  = w1q[5],  B6  = w1q[6],  B7  = w1q[7],  B8  = w1q[8],  B9  = w1q[9];
  uintx4 B10 = w1q[10], B11 = w1q[11], B12 = w1q[12], B13 = w1q[13], B14 = w1q[14];
  uintx4 B15 = w1q[15], B16 = w1q[16], B17 = w1q[17], B18 = w1q[18], B19 = w1q[19];
  uintx4 B20 = w1q[20], B21 = w1q[21], B22 = w1q[22];
  // keep-alives: opaque asm def -> not rematerializable -> must stay in registers
#define KA(x) asm volatile("" : "+v"(x));
  KA(A0) KA(A1) KA(A2) KA(A3) KA(A4) KA(A5) KA(A6) KA(A7) KA(A8) KA(A9) KA(A10)
  KA(A11) KA(A12) KA(A13) KA(A14) KA(A15) KA(A16) KA(A17) KA(A18) KA(A19) KA(A20)
  KA(A21) KA(A22)
  KA(B0) KA(B1) KA(B2) KA(B3) KA(B4) KA(B5) KA(B6) KA(B7) KA(B8) KA(B9) KA(B10)
  KA(B11) KA(B12) KA(B13) KA(B14) KA(B15) KA(B16) KA(B17) KA(B18) KA(B19) KA(B20)
  KA(B21) KA(B22)
#undef KA
  // 18 LDS-resident quads (9 per row), lane-consecutive 16B
#pragma unroll
  for (int q = 0; q < 9; ++q) {
    wl4[q * 512 + tid]       = w0q[23 + q];
    wl4[(9 + q) * 512 + tid] = w1q[23 + q];
  }

  float cst, hlast;
  {
    int gi = b * 1024 + k * 256 + j;
    int si = (k * 64 + b) * 256 + j;
    float hv, cv;
    if (t0 == 0) { hv = h0[gi]; cv = c0[gi]; }
    else         { hv = state[si]; cv = state[65536 + si]; }
    cst = cv; hlast = hv;
    if (half) hl16[j] = (_Float16)hv;   // init hl buffer 0
  }
  __syncthreads();

#define FD2(W, sa, sb) sa = fdot2h(W[0], hq[0], sa); sb = fdot2h(W[1], hq[1], sb); \
                       sa = fdot2h(W[2], hq[2], sa); sb = fdot2h(W[3], hq[3], sb);
#define QVV(q) { uintx4 hq = hl4[hb + q]; FD2(A##q, s0a, s0b) FD2(B##q, s1a, s1b) }
#define QLL(q, l) { uintx4 hq = hl4[hb + q]; \
    uintx4 wa = wl4[(l) * 512 + tid]; uintx4 wb = wl4[(9 + (l)) * 512 + tid]; \
    FD2(wa, s0a, s0b) FD2(wb, s1a, s1b) }

  const _Float16* xgp = xg + (size_t)(k * 64 + b) * 32768;   // 32 steps * 1024 gates (f16)
  _Float16 xa = xgp[r0], xb2 = xgp[r1];
  const size_t outb = (size_t)t0 * 65536 + (size_t)b * 1024 + k * 256 + j;  // + ct*65536
#pragma unroll 1
  for (int ct = 0; ct < 32; ++ct) {
    // store h(ct-1): issued early, ack drains during this step's MAC phase
    if (ct && !half) out[outb + (size_t)(ct - 1) * 65536] = hlast;
    const int hb = (ct & 1) * 32;      // hl read buffer (quads)
    float g0 = (float)xa, g1 = (float)xb2;
    if (ct < 31) { xa = xgp[(ct + 1) * 1024 + r0]; xb2 = xgp[(ct + 1) * 1024 + r1]; }

    float s0a = 0.f, s0b = 0.f, s1a = 0.f, s1b = 0.f;
    QVV(0)  QVV(1)  QVV(2)  QVV(3)  QVV(4)  QVV(5)  QVV(6)  QVV(7)
    QVV(8)  QVV(9)  QVV(10) QVV(11) QVV(12) QVV(13) QVV(14) QVV(15)
    QVV(16) QVV(17) QVV(18) QVV(19) QVV(20) QVV(21) QVV(22)
    QLL(23, 0) QLL(24, 1) QLL(25, 2) QLL(26, 3) QLL(27, 4)
    QLL(28, 5) QLL(29, 6) QLL(30, 7) QLL(31, 8)

    float u0 = g0 + (s0a + s0b);      // half=0: i_j   half=1: g_j
    float u1 = g1 + (s1a + s1b);      // half=0: f_j   half=1: o_j
    float p0 = __shfl_xor(u0, 1, 64);
    float p1 = __shfl_xor(u1, 1, 64);
    float iv = half ? p0 : u0;
    float fv = half ? p1 : u1;
    float gv = half ? u0 : p0;
    float ov = half ? u1 : p1;
    float cn = sigm(fv) * cst + sigm(iv) * tanhf(gv);
    float hn = sigm(ov) * tanhf(cn);
    cst = cn; hlast = hn;
    if (half) hl16[(((ct & 1) ^ 1) << 8) + j] = (_Float16)hn;  // next step's h buffer
    __syncthreads();
  }
#undef FD2
#undef QVV
#undef QLL

  if (!half) {
    out[outb + 31u * 65536] = hlast;   // h(31)
    int si = (k * 64 + b) * 256 + j;
    state[si] = hlast;
    state[65536 + si] = cst;
    if (last) {
      int gi = b * 1024 + k * 256 + j;
      out[33554432 + gi] = hlast;            // new_h
      out[33554432 + 65536 + gi] = cst;      // new_c
    }
  }
}

extern "C" void kernel_launch(void* const* d_in, const int* in_sizes, int n_in,
                              void* d_out, int out_size, void* d_ws, size_t ws_size,
                              hipStream_t stream) {
  const float* x   = (const float*)d_in[0];
  const float* h0  = (const float*)d_in[1];
  const float* c0  = (const float*)d_in[2];
  const float* Wih = (const float*)d_in[3];
  const float* Whh = (const float*)d_in[4];
  const float* bih = (const float*)d_in[5];
  const float* bhh = (const float*)d_in[6];
  float* out = (float*)d_out;
  char* ws = (char*)d_ws;

  // total ws usage: 31,981,568 B (under the known-good 36.2 MB)
  _Float16* xg16  = (_Float16*)ws;                  // 16,777,216 B
  _Float16* xs    = (_Float16*)(ws + 16777216L);    //  8,388,608 B
  _Float16* wih16 = (_Float16*)(ws + 25165824L);    //  4,194,304 B
  uint32*   whh16 = (uint32*)(ws + 29360128L);      //  2,097,152 B (f16 pairs)
  float*    state = (float*)(ws + 31457280L);       //    524,288 B

  // LDS: hl 1024 B + 18*512 weight quads (147456 B) = 148480 B
  hipFuncSetAttribute((const void*)lstm32, hipFuncAttributeMaxDynamicSharedMemorySize, 148480);

  pack_w<<<1024, 256, 0, stream>>>(Wih, Whh, (uint32*)wih16, whh16);
  for (int c = 0; c < 16; ++c) {
    int t0 = c * 32;
    pack_xc<<<2048, 256, 0, stream>>>(x, (uint32*)xs, t0);
    gemm16<<<512, 256, 0, stream>>>(xs, wih16, bih, bhh, xg16);
    lstm32<<<256, 512, 148480, stream>>>(xg16, whh16, h0, c0, out, state, t0, (c == 15) ? 1 : 0);
  }
}